// Round 1
// baseline (476.499 us; speedup 1.0000x reference)
//
#include <hip/hip_runtime.h>

#define NN 50000
#define NE 800000
#define DF 128

// ---- workspace layout (bytes) ----
static const size_t OFF_DEG  = 0;         // u32[NN]
static const size_t OFF_OFFS = 204800;    // u32[NN+1]
static const size_t OFF_CUR  = 409600;    // u32[NN]
static const size_t OFF_CFAC = 614400;    // f32[NN]
static const size_t OFF_CSR  = 819200;    // int2[NE]  (sender, edge)
static const size_t OFF_AN   = 7372800;   // f32[NN*DF]  scaled sum of X[senders]
static const size_t OFF_AE   = 32972800;  // f32[NN*DF]  scaled sum of edge_features
// total ~58.6 MB

__global__ void k_hist(const int* __restrict__ rcv, unsigned* __restrict__ deg) {
    int e = blockIdx.x * blockDim.x + threadIdx.x;
    if (e < NE) atomicAdd(&deg[rcv[e]], 1u);
}

// single-block exclusive scan over deg -> offs; offs[NN] = total
__global__ void k_scan(const unsigned* __restrict__ deg, unsigned* __restrict__ offs) {
    __shared__ unsigned sums[256];
    const int PER = (NN + 255) / 256;  // 196
    int t = threadIdx.x;
    int base = t * PER;
    unsigned s = 0;
    for (int i = 0; i < PER; ++i) {
        int idx = base + i;
        if (idx < NN) s += deg[idx];
    }
    sums[t] = s;
    __syncthreads();
    if (t == 0) {
        unsigned run = 0;
        for (int i = 0; i < 256; ++i) { unsigned v = sums[i]; sums[i] = run; run += v; }
    }
    __syncthreads();
    unsigned run = sums[t];
    for (int i = 0; i < PER; ++i) {
        int idx = base + i;
        if (idx < NN) { offs[idx] = run; run += deg[idx]; }
    }
    if (t == 255) offs[NN] = run;  // == NE
}

__global__ void k_scatter(const int* __restrict__ snd, const int* __restrict__ rcv,
                          const unsigned* __restrict__ offs, unsigned* __restrict__ cur,
                          int2* __restrict__ csr) {
    int e = blockIdx.x * blockDim.x + threadIdx.x;
    if (e >= NE) return;
    int r = rcv[e];
    unsigned p = atomicAdd(&cur[r], 1u);
    csr[offs[r] + p] = make_int2(snd[e], e);
}

// one wave per node: An[n] = (1/d) * sum X[s(e)], Ae[n] = (1/d) * sum ef[e]
__global__ void k_agg(const float* __restrict__ X, const float* __restrict__ EF,
                      const unsigned* __restrict__ offs, const int2* __restrict__ csr,
                      float* __restrict__ An, float* __restrict__ Ae,
                      float* __restrict__ cfac) {
    int wave = threadIdx.x >> 6;
    int lane = threadIdx.x & 63;
    int n = blockIdx.x * 4 + wave;
    if (n >= NN) return;
    unsigned s0 = offs[n], s1 = offs[n + 1];
    int c = lane * 2;
    float anx = 0.f, any = 0.f, aex = 0.f, aey = 0.f;
    for (unsigned p = s0; p < s1; ++p) {
        int2 se = csr[p];
        float2 xv = *reinterpret_cast<const float2*>(X + (size_t)se.x * DF + c);
        float2 ev = *reinterpret_cast<const float2*>(EF + (size_t)se.y * DF + c);
        anx += xv.x; any += xv.y;
        aex += ev.x; aey += ev.y;
    }
    float cnt = (float)(s1 - s0);
    float inv = 1.0f / (cnt + 1e-6f);
    float2 an = make_float2(anx * inv, any * inv);
    float2 ae = make_float2(aex * inv, aey * inv);
    *reinterpret_cast<float2*>(An + (size_t)n * DF + c) = an;
    *reinterpret_cast<float2*>(Ae + (size_t)n * DF + c) = ae;
    if (lane == 0) cfac[n] = cnt * inv;
}

// out[64 rows x 128 cols per block] = X@W[:, :128] + An@W[:,128:] + Ae@We + bias
__global__ __launch_bounds__(256) void k_gemm(
    const float* __restrict__ X, const float* __restrict__ An,
    const float* __restrict__ Ae, const float* __restrict__ W,
    const float* __restrict__ We, const float* __restrict__ bW,
    const float* __restrict__ bWe, const float* __restrict__ cfac,
    float* __restrict__ out) {
    __shared__ float As[64][72];   // [k][m], padded: 18 KiB
    __shared__ float Bs[64][128];  // [k][j]: 32 KiB
    const int tid = threadIdx.x;
    const int m0 = blockIdx.x * 64;

    float acc[8][4];
#pragma unroll
    for (int r = 0; r < 8; ++r)
#pragma unroll
        for (int c = 0; c < 4; ++c) acc[r][c] = 0.f;

    const int tn = (tid & 31) << 2;  // col base (0..124)
    const int tm = (tid >> 5) << 3;  // row base (0..56)

    for (int seg = 0; seg < 3; ++seg) {
        const float* __restrict__ A = (seg == 0) ? X : (seg == 1) ? An : Ae;
        for (int kc = 0; kc < DF; kc += 64) {
            // stage B chunk [64 x 128]
            for (int i = tid; i < 64 * 128; i += 256) {
                int k = i >> 7, j = i & 127;
                float b;
                if (seg == 2) b = We[(kc + k) * 128 + j];
                else          b = W[(kc + k) * 256 + (seg == 1 ? 128 : 0) + j];
                Bs[k][j] = b;
            }
            // stage A chunk transposed [64k x 64m]
            for (int i = tid; i < 64 * 64; i += 256) {
                int m = i >> 6, k = i & 63;
                int gm = m0 + m;
                As[k][m] = (gm < NN) ? A[(size_t)gm * DF + kc + k] : 0.f;
            }
            __syncthreads();
#pragma unroll 4
            for (int k = 0; k < 64; ++k) {
                float4 a0 = *reinterpret_cast<const float4*>(&As[k][tm]);
                float4 a1 = *reinterpret_cast<const float4*>(&As[k][tm + 4]);
                float4 b  = *reinterpret_cast<const float4*>(&Bs[k][tn]);
                float av[8] = {a0.x, a0.y, a0.z, a0.w, a1.x, a1.y, a1.z, a1.w};
                float bv[4] = {b.x, b.y, b.z, b.w};
#pragma unroll
                for (int r = 0; r < 8; ++r)
#pragma unroll
                    for (int c = 0; c < 4; ++c)
                        acc[r][c] = fmaf(av[r], bv[c], acc[r][c]);
            }
            __syncthreads();
        }
    }

    // epilogue: add biases; cnt/d factor on (b_xj + b_We)
#pragma unroll
    for (int r = 0; r < 8; ++r) {
        int gm = m0 + tm + r;
        if (gm >= NN) continue;
        float cf = cfac[gm];
        float4 o;
        o.x = acc[r][0] + bW[tn + 0] + cf * (bW[128 + tn + 0] + bWe[tn + 0]);
        o.y = acc[r][1] + bW[tn + 1] + cf * (bW[128 + tn + 1] + bWe[tn + 1]);
        o.z = acc[r][2] + bW[tn + 2] + cf * (bW[128 + tn + 2] + bWe[tn + 2]);
        o.w = acc[r][3] + bW[tn + 3] + cf * (bW[128 + tn + 3] + bWe[tn + 3]);
        *reinterpret_cast<float4*>(&out[(size_t)gm * DF + tn]) = o;
    }
}

extern "C" void kernel_launch(void* const* d_in, const int* in_sizes, int n_in,
                              void* d_out, int out_size, void* d_ws, size_t ws_size,
                              hipStream_t stream) {
    const float* X   = (const float*)d_in[0];
    const int*   snd = (const int*)d_in[1];
    const int*   rcv = (const int*)d_in[2];
    const float* EF  = (const float*)d_in[3];
    const float* W   = (const float*)d_in[4];
    const float* bW  = (const float*)d_in[5];
    const float* We  = (const float*)d_in[6];
    const float* bWe = (const float*)d_in[7];
    float* out = (float*)d_out;

    char* ws = (char*)d_ws;
    unsigned* deg  = (unsigned*)(ws + OFF_DEG);
    unsigned* offs = (unsigned*)(ws + OFF_OFFS);
    unsigned* cur  = (unsigned*)(ws + OFF_CUR);
    float*    cfac = (float*)(ws + OFF_CFAC);
    int2*     csr  = (int2*)(ws + OFF_CSR);
    float*    An   = (float*)(ws + OFF_AN);
    float*    Ae   = (float*)(ws + OFF_AE);

    hipMemsetAsync(deg, 0, NN * sizeof(unsigned), stream);
    hipMemsetAsync(cur, 0, NN * sizeof(unsigned), stream);

    k_hist<<<(NE + 255) / 256, 256, 0, stream>>>(rcv, deg);
    k_scan<<<1, 256, 0, stream>>>(deg, offs);
    k_scatter<<<(NE + 255) / 256, 256, 0, stream>>>(snd, rcv, offs, cur, csr);
    k_agg<<<(NN + 3) / 4, 256, 0, stream>>>(X, EF, offs, csr, An, Ae, cfac);
    k_gemm<<<(NN + 63) / 64, 256, 0, stream>>>(X, An, Ae, W, We, bW, bWe, cfac, out);
}

// Round 2
// 355.040 us; speedup vs baseline: 1.3421x; 1.3421x over previous
//
#include <hip/hip_runtime.h>

#define NN 50000
#define NE 800000
#define DF 128
#define KTOT 384
#define MPAD 50048  // 782 * 64

typedef __attribute__((ext_vector_type(8))) short bf16x8;
typedef __attribute__((ext_vector_type(4))) float f32x4;

// ---- workspace layout (bytes) ----
static const size_t OFF_DEG  = 0;         // u32[NN]
static const size_t OFF_OFFS = 204800;    // u32[NN+1]
static const size_t OFF_CUR  = 409600;    // u32[NN]
static const size_t OFF_CFAC = 614400;    // f32[NN]
static const size_t OFF_CSR  = 819200;    // int2[NE]
static const size_t OFF_BCT  = 7372800;   // bf16[128][384]
static const size_t OFF_ACAT = 7475200;   // bf16[MPAD][384]
// total ~45.9 MB

__device__ __forceinline__ unsigned short f2bf(float f) {
    unsigned u = __float_as_uint(f);
    return (unsigned short)((u + 0x7FFFu + ((u >> 16) & 1u)) >> 16);
}

__global__ void k_hist(const int* __restrict__ rcv, unsigned* __restrict__ deg) {
    int e = blockIdx.x * blockDim.x + threadIdx.x;
    if (e < NE) atomicAdd(&deg[rcv[e]], 1u);
}

__global__ void k_scan(const unsigned* __restrict__ deg, unsigned* __restrict__ offs) {
    __shared__ unsigned sums[256];
    const int PER = (NN + 255) / 256;
    int t = threadIdx.x;
    int base = t * PER;
    unsigned s = 0;
    for (int i = 0; i < PER; ++i) {
        int idx = base + i;
        if (idx < NN) s += deg[idx];
    }
    sums[t] = s;
    __syncthreads();
    if (t == 0) {
        unsigned run = 0;
        for (int i = 0; i < 256; ++i) { unsigned v = sums[i]; sums[i] = run; run += v; }
    }
    __syncthreads();
    unsigned run = sums[t];
    for (int i = 0; i < PER; ++i) {
        int idx = base + i;
        if (idx < NN) { offs[idx] = run; run += deg[idx]; }
    }
    if (t == 255) offs[NN] = run;
}

__global__ void k_scatter(const int* __restrict__ snd, const int* __restrict__ rcv,
                          const unsigned* __restrict__ offs, unsigned* __restrict__ cur,
                          int2* __restrict__ csr) {
    int e = blockIdx.x * blockDim.x + threadIdx.x;
    if (e >= NE) return;
    int r = rcv[e];
    unsigned p = atomicAdd(&cur[r], 1u);
    csr[offs[r] + p] = make_int2(snd[e], e);
}

// X (fp32) -> bf16 into Acat cols 0..127; zero-fill pad rows entirely
__global__ void k_prep_x(const float* __restrict__ X, unsigned short* __restrict__ Acat) {
    int idx = blockIdx.x * blockDim.x + threadIdx.x;
    int row = idx >> 5, q = idx & 31;
    if (row >= MPAD) return;
    unsigned short* dst = Acat + (size_t)row * KTOT;
    if (row < NN) {
        float4 v = *reinterpret_cast<const float4*>(X + (size_t)row * DF + q * 4);
        unsigned lo = (unsigned)f2bf(v.x) | ((unsigned)f2bf(v.y) << 16);
        unsigned hi = (unsigned)f2bf(v.z) | ((unsigned)f2bf(v.w) << 16);
        uint2 pk; pk.x = lo; pk.y = hi;
        *reinterpret_cast<uint2*>(dst + q * 4) = pk;
    } else {
        // zero all 384 cols of pad rows (12 shorts per thread)
        for (int i = 0; i < 12; ++i) dst[q * 12 + i] = 0;
    }
}

// W/We (fp32) -> bf16 transposed BcT[n][k], k: 0-127=W[:, :128], 128-255=W[:,128:], 256-383=We
__global__ void k_prep_w(const float* __restrict__ W, const float* __restrict__ We,
                         unsigned short* __restrict__ BcT) {
    int idx = blockIdx.x * blockDim.x + threadIdx.x;
    if (idx >= 128 * KTOT) return;
    int n = idx / KTOT, k = idx - n * KTOT;
    float v;
    if (k < 128)      v = W[k * 256 + n];
    else if (k < 256) v = W[(k - 128) * 256 + 128 + n];
    else              v = We[(k - 256) * 128 + n];
    BcT[idx] = f2bf(v);
}

// one wave per node: Acat[n][128..255] = bf16((1/d) sum X[s]), [256..383] = bf16((1/d) sum EF[e])
__global__ void k_agg(const float* __restrict__ X, const float* __restrict__ EF,
                      const unsigned* __restrict__ offs, const int2* __restrict__ csr,
                      unsigned short* __restrict__ Acat, float* __restrict__ cfac) {
    int n = __builtin_amdgcn_readfirstlane(blockIdx.x * 4 + (threadIdx.x >> 6));
    int lane = threadIdx.x & 63;
    if (n >= NN) return;
    unsigned s0 = offs[n], s1 = offs[n + 1];
    int c = lane * 2;
    float anx = 0.f, any = 0.f, aex = 0.f, aey = 0.f;
    unsigned p = s0;
    for (; p + 2 <= s1; p += 2) {
        int2 e0 = csr[p], e1 = csr[p + 1];
        float2 x0 = *reinterpret_cast<const float2*>(X + (size_t)e0.x * DF + c);
        float2 v0 = *reinterpret_cast<const float2*>(EF + (size_t)e0.y * DF + c);
        float2 x1 = *reinterpret_cast<const float2*>(X + (size_t)e1.x * DF + c);
        float2 v1 = *reinterpret_cast<const float2*>(EF + (size_t)e1.y * DF + c);
        anx += x0.x + x1.x; any += x0.y + x1.y;
        aex += v0.x + v1.x; aey += v0.y + v1.y;
    }
    if (p < s1) {
        int2 e0 = csr[p];
        float2 x0 = *reinterpret_cast<const float2*>(X + (size_t)e0.x * DF + c);
        float2 v0 = *reinterpret_cast<const float2*>(EF + (size_t)e0.y * DF + c);
        anx += x0.x; any += x0.y; aex += v0.x; aey += v0.y;
    }
    float cnt = (float)(s1 - s0);
    float inv = 1.0f / (cnt + 1e-6f);
    unsigned short* row = Acat + (size_t)n * KTOT;
    *reinterpret_cast<unsigned*>(row + 128 + c) =
        (unsigned)f2bf(anx * inv) | ((unsigned)f2bf(any * inv) << 16);
    *reinterpret_cast<unsigned*>(row + 256 + c) =
        (unsigned)f2bf(aex * inv) | ((unsigned)f2bf(aey * inv) << 16);
    if (lane == 0) cfac[n] = cnt * inv;
}

// MFMA GEMM, no LDS: out[MPAD x 128] = Acat @ BcT^T (+ bias epilogue)
// block = 4 waves; wave (w&1) -> 32-row half, (w>>1) -> 64-col half; per wave 2x4 16x16 frags
__global__ __launch_bounds__(256) void k_gemm(
    const unsigned short* __restrict__ Acat, const unsigned short* __restrict__ BcT,
    const float* __restrict__ bW, const float* __restrict__ bWe,
    const float* __restrict__ cfac, float* __restrict__ out) {
    const int tid = threadIdx.x;
    const int wave = tid >> 6, lane = tid & 63;
    const int l15 = lane & 15, l4 = lane >> 4;
    const int mbase = blockIdx.x * 64 + (wave & 1) * 32;
    const int n0 = (wave >> 1) * 64;

    f32x4 acc[2][4];
#pragma unroll
    for (int mg = 0; mg < 2; ++mg)
#pragma unroll
        for (int ng = 0; ng < 4; ++ng) acc[mg][ng] = (f32x4){0.f, 0.f, 0.f, 0.f};

    const unsigned short* arow0 = Acat + (size_t)(mbase + l15) * KTOT + l4 * 8;
    const unsigned short* arow1 = arow0 + 16 * KTOT;
    const unsigned short* brow = BcT + (size_t)(n0 + l15) * KTOT + l4 * 8;

#pragma unroll 4
    for (int kk = 0; kk < 12; ++kk) {
        bf16x8 a0 = *reinterpret_cast<const bf16x8*>(arow0 + kk * 32);
        bf16x8 a1 = *reinterpret_cast<const bf16x8*>(arow1 + kk * 32);
        bf16x8 b0 = *reinterpret_cast<const bf16x8*>(brow + kk * 32);
        bf16x8 b1 = *reinterpret_cast<const bf16x8*>(brow + 16 * KTOT + kk * 32);
        bf16x8 b2 = *reinterpret_cast<const bf16x8*>(brow + 32 * KTOT + kk * 32);
        bf16x8 b3 = *reinterpret_cast<const bf16x8*>(brow + 48 * KTOT + kk * 32);
        acc[0][0] = __builtin_amdgcn_mfma_f32_16x16x32_bf16(a0, b0, acc[0][0], 0, 0, 0);
        acc[0][1] = __builtin_amdgcn_mfma_f32_16x16x32_bf16(a0, b1, acc[0][1], 0, 0, 0);
        acc[0][2] = __builtin_amdgcn_mfma_f32_16x16x32_bf16(a0, b2, acc[0][2], 0, 0, 0);
        acc[0][3] = __builtin_amdgcn_mfma_f32_16x16x32_bf16(a0, b3, acc[0][3], 0, 0, 0);
        acc[1][0] = __builtin_amdgcn_mfma_f32_16x16x32_bf16(a1, b0, acc[1][0], 0, 0, 0);
        acc[1][1] = __builtin_amdgcn_mfma_f32_16x16x32_bf16(a1, b1, acc[1][1], 0, 0, 0);
        acc[1][2] = __builtin_amdgcn_mfma_f32_16x16x32_bf16(a1, b2, acc[1][2], 0, 0, 0);
        acc[1][3] = __builtin_amdgcn_mfma_f32_16x16x32_bf16(a1, b3, acc[1][3], 0, 0, 0);
    }

#pragma unroll
    for (int mg = 0; mg < 2; ++mg) {
#pragma unroll
        for (int ng = 0; ng < 4; ++ng) {
            int col = n0 + ng * 16 + l15;
            float bx = bW[col];
            float bj = bW[128 + col] + bWe[col];
#pragma unroll
            for (int j = 0; j < 4; ++j) {
                int row = mbase + mg * 16 + l4 * 4 + j;
                if (row < NN)
                    out[(size_t)row * DF + col] = acc[mg][ng][j] + bx + cfac[row] * bj;
            }
        }
    }
}

extern "C" void kernel_launch(void* const* d_in, const int* in_sizes, int n_in,
                              void* d_out, int out_size, void* d_ws, size_t ws_size,
                              hipStream_t stream) {
    const float* X   = (const float*)d_in[0];
    const int*   snd = (const int*)d_in[1];
    const int*   rcv = (const int*)d_in[2];
    const float* EF  = (const float*)d_in[3];
    const float* W   = (const float*)d_in[4];
    const float* bW  = (const float*)d_in[5];
    const float* We  = (const float*)d_in[6];
    const float* bWe = (const float*)d_in[7];
    float* out = (float*)d_out;

    char* ws = (char*)d_ws;
    unsigned* deg  = (unsigned*)(ws + OFF_DEG);
    unsigned* offs = (unsigned*)(ws + OFF_OFFS);
    unsigned* cur  = (unsigned*)(ws + OFF_CUR);
    float*    cfac = (float*)(ws + OFF_CFAC);
    int2*     csr  = (int2*)(ws + OFF_CSR);
    unsigned short* BcT  = (unsigned short*)(ws + OFF_BCT);
    unsigned short* Acat = (unsigned short*)(ws + OFF_ACAT);

    hipMemsetAsync(deg, 0, NN * sizeof(unsigned), stream);
    hipMemsetAsync(cur, 0, NN * sizeof(unsigned), stream);

    k_prep_x<<<(MPAD * 32 + 255) / 256, 256, 0, stream>>>(X, Acat);
    k_prep_w<<<(128 * KTOT + 255) / 256, 256, 0, stream>>>(W, We, BcT);
    k_hist<<<(NE + 255) / 256, 256, 0, stream>>>(rcv, deg);
    k_scan<<<1, 256, 0, stream>>>(deg, offs);
    k_scatter<<<(NE + 255) / 256, 256, 0, stream>>>(snd, rcv, offs, cur, csr);
    k_agg<<<(NN + 3) / 4, 256, 0, stream>>>(X, EF, offs, csr, Acat, cfac);
    k_gemm<<<MPAD / 64, 256, 0, stream>>>(Acat, BcT, bW, bWe, cfac, out);
}